// Round 1
// baseline (531.796 us; speedup 1.0000x reference)
//
#include <hip/hip_runtime.h>

#define HID 128
#define CLS 10

// ---------------- CSR build ----------------

__global__ __launch_bounds__(256) void zero_init(int* degi, int* fillc, int n) {
  int i = blockIdx.x * 256 + threadIdx.x;
  if (i < n) { degi[i] = 0; fillc[i] = 0; }
}

__global__ __launch_bounds__(256) void degree_k(const int* __restrict__ dst,
                                                int* __restrict__ degi, int E) {
  int e = blockIdx.x * 256 + threadIdx.x;
  if (e < E) atomicAdd(&degi[dst[e]], 1);
}

__global__ __launch_bounds__(256) void dinv_k(const int* __restrict__ degi,
                                              float* __restrict__ dinv, int n) {
  int i = blockIdx.x * 256 + threadIdx.x;
  if (i < n) dinv[i] = rsqrtf((float)degi[i] + 1.0f);  // +1 for self-loop
}

__global__ __launch_bounds__(256) void scan_chunk(const int* __restrict__ degi,
                                                  int* __restrict__ row_ptr,
                                                  int* __restrict__ blockSums, int n) {
  __shared__ int sd[256];
  int t = threadIdx.x;
  int i = blockIdx.x * 256 + t;
  int v = (i < n) ? degi[i] : 0;
  sd[t] = v;
  for (int off = 1; off < 256; off <<= 1) {
    __syncthreads();
    int x = (t >= off) ? sd[t - off] : 0;
    __syncthreads();
    sd[t] += x;
  }
  if (i < n) row_ptr[i] = sd[t] - v;  // exclusive within chunk
  if (t == 255) blockSums[blockIdx.x] = sd[255];
}

__global__ __launch_bounds__(256) void scan_top(int* blockSums, int nb) {
  __shared__ int sd[256];
  int t = threadIdx.x;
  int v = (t < nb) ? blockSums[t] : 0;
  sd[t] = v;
  for (int off = 1; off < 256; off <<= 1) {
    __syncthreads();
    int x = (t >= off) ? sd[t - off] : 0;
    __syncthreads();
    sd[t] += x;
  }
  if (t < nb) blockSums[t] = sd[t] - v;  // exclusive block offsets
}

__global__ __launch_bounds__(256) void scan_add(int* __restrict__ row_ptr,
                                                const int* __restrict__ blockSums,
                                                int n, int E) {
  int i = blockIdx.x * 256 + threadIdx.x;
  if (i < n) row_ptr[i] += blockSums[blockIdx.x];
  if (i == 0) row_ptr[n] = E;
}

__global__ __launch_bounds__(256) void csr_fill(const int* __restrict__ src,
                                                const int* __restrict__ dst,
                                                const float* __restrict__ dinv,
                                                const int* __restrict__ row_ptr,
                                                int* __restrict__ fillc,
                                                int* __restrict__ col_src,
                                                float* __restrict__ edge_w, int E) {
  int e = blockIdx.x * 256 + threadIdx.x;
  if (e >= E) return;
  int s = src[e], d = dst[e];
  int slot = atomicAdd(&fillc[d], 1);
  int idx = row_ptr[d] + slot;
  col_src[idx] = s;
  edge_w[idx] = dinv[s] * dinv[d];
}

// ---------------- fp32 GEMM: T[n,128] = A[n,128] @ W[128,128] ----------------
// Block tile: 64 rows x 64 cols (gridDim.y = 2 col-halves). 64 KB LDS total.
// Thread: 8 rows x 2 cols. Waves see 2 distinct sA row addrs (2-way = free).

__global__ __launch_bounds__(256) void gemm128(const float* __restrict__ A,
                                               const float* __restrict__ W,
                                               float* __restrict__ T, int nrows) {
  __shared__ float sA[64 * 128];  // 32 KB
  __shared__ float sW[128 * 64];  // 32 KB
  int tid = threadIdx.x;
  int row0 = blockIdx.x * 64;
  int col0 = blockIdx.y * 64;

  for (int i = tid * 4; i < 128 * 64; i += 1024) {
    int k = i >> 6, cc = i & 63;
    *(float4*)&sW[i] = *(const float4*)&W[k * 128 + col0 + cc];
  }
  for (int i = tid * 4; i < 64 * 128; i += 1024) {
    int r = i >> 7;
    int gr = row0 + r;
    float4 v = make_float4(0.f, 0.f, 0.f, 0.f);
    if (gr < nrows) v = *(const float4*)&A[gr * 128 + (i & 127)];
    *(float4*)&sA[i] = v;
  }
  __syncthreads();

  int ry = (tid >> 5) * 8;   // 8 row-groups of 8
  int cx = (tid & 31) * 2;   // 32 col-groups of 2
  float2 acc[8];
#pragma unroll
  for (int r = 0; r < 8; ++r) acc[r] = make_float2(0.f, 0.f);

  for (int k0 = 0; k0 < 128; k0 += 4) {
    float4 a[8];
#pragma unroll
    for (int r = 0; r < 8; ++r) a[r] = *(float4*)&sA[(ry + r) * 128 + k0];
#pragma unroll
    for (int kk = 0; kk < 4; ++kk) {
      float2 w = *(float2*)&sW[(k0 + kk) * 64 + cx];
#pragma unroll
      for (int r = 0; r < 8; ++r) {
        float av = (kk == 0) ? a[r].x : (kk == 1) ? a[r].y : (kk == 2) ? a[r].z : a[r].w;
        acc[r].x += av * w.x;
        acc[r].y += av * w.y;
      }
    }
  }
#pragma unroll
  for (int r = 0; r < 8; ++r) {
    int gr = row0 + ry + r;
    if (gr < nrows) *(float2*)&T[gr * 128 + col0 + cx] = acc[r];
  }
}

// ---------------- aggregate: out[n] = relu(b + dinv[n]^2*T[n] + sum_e w_e*T[src_e]) ----------------
// One wave per node, 2 cols per lane.

__global__ __launch_bounds__(256) void aggregate(const float* __restrict__ T,
                                                 const float* __restrict__ dinv,
                                                 const int* __restrict__ row_ptr,
                                                 const int* __restrict__ col_src,
                                                 const float* __restrict__ edge_w,
                                                 const float* __restrict__ bias,
                                                 float* __restrict__ Hout, int n) {
  int node = (blockIdx.x * 256 + threadIdx.x) >> 6;
  if (node >= n) return;
  int lane = threadIdx.x & 63;
  int c = lane * 2;
  float di = dinv[node];
  float2 t0 = *(const float2*)&T[node * HID + c];
  float ax = di * di * t0.x;
  float ay = di * di * t0.y;
  int j = row_ptr[node], end = row_ptr[node + 1];
  for (; j + 4 <= end; j += 4) {
    int s0 = col_src[j], s1 = col_src[j + 1], s2 = col_src[j + 2], s3 = col_src[j + 3];
    float w0 = edge_w[j], w1 = edge_w[j + 1], w2 = edge_w[j + 2], w3 = edge_w[j + 3];
    float2 v0 = *(const float2*)&T[s0 * HID + c];
    float2 v1 = *(const float2*)&T[s1 * HID + c];
    float2 v2 = *(const float2*)&T[s2 * HID + c];
    float2 v3 = *(const float2*)&T[s3 * HID + c];
    ax += w0 * v0.x + w1 * v1.x + w2 * v2.x + w3 * v3.x;
    ay += w0 * v0.y + w1 * v1.y + w2 * v2.y + w3 * v3.y;
  }
  for (; j < end; ++j) {
    int s = col_src[j];
    float w = edge_w[j];
    float2 v = *(const float2*)&T[s * HID + c];
    ax += w * v.x;
    ay += w * v.y;
  }
  ax = fmaxf(ax + bias[c], 0.f);
  ay = fmaxf(ay + bias[c + 1], 0.f);
  *(float2*)&Hout[node * HID + c] = make_float2(ax, ay);
}

// ---------------- pool (mean per graph) + classifier ----------------

__global__ __launch_bounds__(128) void pool_classify(const float* __restrict__ Hin,
                                                     const int* __restrict__ batch,
                                                     const float* __restrict__ Wl,
                                                     const float* __restrict__ bl,
                                                     float* __restrict__ out, int n) {
  int g = blockIdx.x;
  int t = threadIdx.x;
  // lower_bound(batch, g) and lower_bound(batch, g+1) — batch is sorted
  int s = 0, e = n;
  {
    int lo = 0, hi = n;
    while (lo < hi) { int mid = (lo + hi) >> 1; if (batch[mid] < g) lo = mid + 1; else hi = mid; }
    s = lo;
    lo = s; hi = n;
    while (lo < hi) { int mid = (lo + hi) >> 1; if (batch[mid] < g + 1) lo = mid + 1; else hi = mid; }
    e = lo;
  }
  float acc = 0.f;
  for (int i = s; i < e; ++i) acc += Hin[i * HID + t];
  float cnt = (float)(e - s);
  acc /= fmaxf(cnt, 1.0f);
  __shared__ float p[HID];
  p[t] = acc;
  __syncthreads();
  if (t < CLS) {
    float o = bl[t];
    for (int j = 0; j < HID; ++j) o += p[j] * Wl[j * CLS + t];
    out[g * CLS + t] = o;
  }
}

// ---------------- launch ----------------

extern "C" void kernel_launch(void* const* d_in, const int* in_sizes, int n_in,
                              void* d_out, int out_size, void* d_ws, size_t ws_size,
                              hipStream_t stream) {
  const float* x  = (const float*)d_in[0];
  const float* W1 = (const float*)d_in[1];
  const float* b1 = (const float*)d_in[2];
  const float* W2 = (const float*)d_in[3];
  const float* b2 = (const float*)d_in[4];
  const float* W3 = (const float*)d_in[5];
  const float* b3 = (const float*)d_in[6];
  const float* Wl = (const float*)d_in[7];
  const float* bl = (const float*)d_in[8];
  const int* edge_index = (const int*)d_in[9];
  const int* batch = (const int*)d_in[10];

  const int N = in_sizes[10];
  const int E = in_sizes[9] / 2;
  const int G = out_size / CLS;
  const int* src = edge_index;
  const int* dst = edge_index + E;

  // workspace carve (256B aligned)
  uintptr_t p = (uintptr_t)d_ws;
  auto take = [&](size_t bytes) -> void* {
    void* r = (void*)p;
    p += (bytes + 255) & ~(size_t)255;
    return r;
  };
  int*   degi      = (int*)take((size_t)N * 4);
  int*   fillc     = (int*)take((size_t)N * 4);
  int*   row_ptr   = (int*)take((size_t)(N + 1) * 4);
  int*   blockSums = (int*)take(256 * 4);
  float* dinv      = (float*)take((size_t)N * 4);
  int*   col_src   = (int*)take((size_t)E * 4);
  float* edge_w    = (float*)take((size_t)E * 4);
  float* bufT      = (float*)take((size_t)N * HID * 4);
  float* bufH      = (float*)take((size_t)N * HID * 4);

  int nbN = (N + 255) / 256;
  int nbE = (E + 255) / 256;

  zero_init<<<nbN, 256, 0, stream>>>(degi, fillc, N);
  degree_k<<<nbE, 256, 0, stream>>>(dst, degi, E);
  dinv_k<<<nbN, 256, 0, stream>>>(degi, dinv, N);
  scan_chunk<<<nbN, 256, 0, stream>>>(degi, row_ptr, blockSums, N);
  scan_top<<<1, 256, 0, stream>>>(blockSums, nbN);
  scan_add<<<nbN, 256, 0, stream>>>(row_ptr, blockSums, N, E);
  csr_fill<<<nbE, 256, 0, stream>>>(src, dst, dinv, row_ptr, fillc, col_src, edge_w, E);

  dim3 ggrid((N + 63) / 64, 2);
  int aggBlocks = (N * 64 + 255) / 256;

  // layer 1
  gemm128<<<ggrid, 256, 0, stream>>>(x, W1, bufT, N);
  aggregate<<<aggBlocks, 256, 0, stream>>>(bufT, dinv, row_ptr, col_src, edge_w, b1, bufH, N);
  // layer 2
  gemm128<<<ggrid, 256, 0, stream>>>(bufH, W2, bufT, N);
  aggregate<<<aggBlocks, 256, 0, stream>>>(bufT, dinv, row_ptr, col_src, edge_w, b2, bufH, N);
  // layer 3
  gemm128<<<ggrid, 256, 0, stream>>>(bufH, W3, bufT, N);
  aggregate<<<aggBlocks, 256, 0, stream>>>(bufT, dinv, row_ptr, col_src, edge_w, b3, bufH, N);

  pool_classify<<<G, 128, 0, stream>>>(bufH, batch, Wl, bl, (float*)d_out, N);
}